// Round 4
// baseline (518.883 us; speedup 1.0000x reference)
//
#include <hip/hip_runtime.h>

// VQ argmin: exact bit-level emulation of numpy fp32 reference:
//   A  = np.sum(flat*flat, axis=1)     (numpy pairwise-sum tree, fp32)
//   M2 = (2*flat) @ emb.T              (BLAS: sequential fp32 fma chain over d)
//   dist = (A - M2) + ee;  argmin_k (first-min ties)
// z_e_x: [B=16, D=256, H=64, W=64] fp32; embedding: [K=1024, D=256] fp32
// out: int32 [65536]
//
// R4: SGPR-broadcast GEMV kept; tile reshaped Rn=2 x KT=32 so the scalar
// e-stream double-buffers within the SGPR budget (32+32 live vs 64+64 before).
// e packed sequentially per (split,kt): 128 B/dd stream, 32 KB/pass.
// NSPLIT=8: same-XCD blocks share one 128 KB e-slab in L2.

#define D_DIM  256
#define K_DIM  1024
#define HW     4096
#define N_TOT  65536
#define NSPLIT 8
#define KSPL   (K_DIM / NSPLIT)   // 128
#define KT     32                 // k per acc group
#define NKT    (KSPL / KT)        // 4
#define F32MAX 3.402823466e38f

// ---- numpy pairwise_sum replication (n=256 = two 128-blocks of 8 accumulators)

__global__ void ee_kernel(const float* __restrict__ e, float* __restrict__ ee) {
#pragma clang fp contract(off)
    int k = blockIdx.x * blockDim.x + threadIdx.x;
    if (k >= K_DIM) return;
    const float* row = e + (size_t)k * D_DIM;
    float total = 0.0f;
    #pragma unroll
    for (int h = 0; h < 2; ++h) {
        const float* a = row + h * 128;
        float r[8];
        #pragma unroll
        for (int j = 0; j < 8; ++j) { float v = a[j]; r[j] = v * v; }
        #pragma unroll
        for (int i = 8; i < 128; i += 8) {
            #pragma unroll
            for (int j = 0; j < 8; ++j) { float v = a[i + j]; r[j] = r[j] + v * v; }
        }
        float s = ((r[0] + r[1]) + (r[2] + r[3])) + ((r[4] + r[5]) + (r[6] + r[7]));
        total = (h == 0) ? s : (total + s);
    }
    ee[k] = total;
}

__global__ void a_kernel(const float* __restrict__ z, float* __restrict__ A) {
#pragma clang fp contract(off)
    int n = blockIdx.x * blockDim.x + threadIdx.x;
    int b  = n >> 12;
    int hw = n & (HW - 1);
    const float* base = z + (size_t)b * D_DIM * HW + hw;
    float total = 0.0f;
    #pragma unroll
    for (int h = 0; h < 2; ++h) {
        float r[8];
        #pragma unroll
        for (int j = 0; j < 8; ++j) {
            float v = base[(size_t)(h * 128 + j) * HW];
            r[j] = v * v;
        }
        #pragma unroll
        for (int i = 8; i < 128; i += 8) {
            #pragma unroll
            for (int j = 0; j < 8; ++j) {
                float v = base[(size_t)(h * 128 + i + j) * HW];
                r[j] = r[j] + v * v;
            }
        }
        float s = ((r[0] + r[1]) + (r[2] + r[3])) + ((r[4] + r[5]) + (r[6] + r[7]));
        total = (h == 0) ? s : (total + s);
    }
    A[n] = total;
}

// ---- pack: epk[s][kt][d][KT] = 2*emb[k][d], k = s*KSPL + kt*KT + j
// sequential 128B/dd scalar stream per (s,kt) pass; x2 folded (bitwise-equal)

__global__ void pack_kernel(const float* __restrict__ e, float* __restrict__ epk) {
    int k = blockIdx.x;       // 0..1023
    int d = threadIdx.x;      // 0..255
    int s  = k >> 7;
    int kt = (k >> 5) & (NKT - 1);
    int j  = k & (KT - 1);
    epk[(((size_t)(s * NKT + kt) * D_DIM + d) * KT) + j] = 2.0f * e[(size_t)k * D_DIM + d];
}

// ---- main: 2 n per thread, 32-k acc tile, e via SGPR stream, no LDS

__launch_bounds__(256, 4)
__global__ void vq_partial(const float* __restrict__ z, const float* __restrict__ epk,
                           const float* __restrict__ A, const float* __restrict__ ee,
                           float* __restrict__ pv, int* __restrict__ pk) {
#pragma clang fp contract(off)
    const int tid  = threadIdx.x;
    const int s    = blockIdx.x & (NSPLIT - 1);   // round-robin: same-XCD -> same s
    const int slab = blockIdx.x >> 3;             // 0..127, 512 n per slab
    const int n0   = slab * 512 + tid;
    const int n1   = n0 + 256;
    const int b    = n0 >> 12;                    // 512 | 4096: slab within one batch
    const float* __restrict__ zp0 = z + (size_t)b * D_DIM * HW + (n0 & (HW - 1));
    const float* __restrict__ zp1 = z + (size_t)b * D_DIM * HW + (n1 & (HW - 1));
    const float* __restrict__ ebase = epk + (size_t)s * (NKT * D_DIM * KT);

    const float An0 = A[n0];
    const float An1 = A[n1];
    float best0 = F32MAX, best1 = F32MAX;
    int   bk0 = 0, bk1 = 0;

    // z ping-pong: 8 d's per half per n; (mod 256) wrap re-primes next pass
    float za0[8], za1[8], zb0[8], zb1[8];
    #pragma unroll
    for (int i = 0; i < 8; ++i) {
        za0[i] = zp0[(size_t)i * HW];
        za1[i] = zp1[(size_t)i * HW];
    }

    #pragma unroll 1
    for (int kt = 0; kt < NKT; ++kt) {
        const float* __restrict__ ek = ebase + (size_t)kt * (D_DIM * KT);
        float a0[KT], a1[KT];
        #pragma unroll
        for (int j = 0; j < KT; ++j) { a0[j] = 0.0f; a1[j] = 0.0f; }

        #pragma unroll 1
        for (int it = 0; it < 16; ++it) {
            const int base = it * 16;
            // prefetch d = base+8 .. base+15
            #pragma unroll
            for (int i = 0; i < 8; ++i) {
                const size_t idx = (size_t)((base + 8 + i) & (D_DIM - 1)) * HW;
                zb0[i] = zp0[idx];
                zb1[i] = zp1[idx];
            }
            // compute d = base .. base+7 (ascending: exact chain)
            #pragma unroll
            for (int dd = 0; dd < 8; ++dd) {
                const float zv0 = za0[dd], zv1 = za1[dd];
                const float* __restrict__ er = ek + (size_t)(base + dd) * KT;
                #pragma unroll
                for (int j = 0; j < KT; ++j) {
                    const float ev = er[j];           // wave-uniform -> SGPR
                    a0[j] = fmaf(zv0, ev, a0[j]);
                    a1[j] = fmaf(zv1, ev, a1[j]);
                }
            }
            // prefetch d = base+16 .. base+23 (mod 256)
            #pragma unroll
            for (int i = 0; i < 8; ++i) {
                const size_t idx = (size_t)((base + 16 + i) & (D_DIM - 1)) * HW;
                za0[i] = zp0[idx];
                za1[i] = zp1[idx];
            }
            // compute d = base+8 .. base+15
            #pragma unroll
            for (int dd = 0; dd < 8; ++dd) {
                const float zv0 = zb0[dd], zv1 = zb1[dd];
                const float* __restrict__ er = ek + (size_t)(base + 8 + dd) * KT;
                #pragma unroll
                for (int j = 0; j < KT; ++j) {
                    const float ev = er[j];
                    a0[j] = fmaf(zv0, ev, a0[j]);
                    a1[j] = fmaf(zv1, ev, a1[j]);
                }
            }
        }

        // epilogue: dist = (An - M2) + ee, k ascending -> first-min ties
        const int kbase = s * KSPL + kt * KT;
        #pragma unroll
        for (int j = 0; j < KT; ++j) {
            const int kg = kbase + j;
            const float eev = ee[kg];                 // uniform -> SGPR
            const float d0 = (An0 - a0[j]) + eev;
            const float d1 = (An1 - a1[j]) + eev;
            if (d0 < best0) { best0 = d0; bk0 = kg; }
            if (d1 < best1) { best1 = d1; bk1 = kg; }
        }
    }

    pv[(size_t)s * N_TOT + n0] = best0;
    pk[(size_t)s * N_TOT + n0] = bk0;
    pv[(size_t)s * N_TOT + n1] = best1;
    pk[(size_t)s * N_TOT + n1] = bk1;
}

// ---- exact cross-split combine (splits ascending in k; strict < keeps lowest)

__global__ void combine_kernel(const float* __restrict__ pv, const int* __restrict__ pk,
                               int* __restrict__ out) {
    int n = blockIdx.x * blockDim.x + threadIdx.x;
    float bv = pv[n];
    int   bk = pk[n];
    #pragma unroll
    for (int s2 = 1; s2 < NSPLIT; ++s2) {
        float v = pv[(size_t)s2 * N_TOT + n];
        int   k = pk[(size_t)s2 * N_TOT + n];
        if (v < bv) { bv = v; bk = k; }
    }
    out[n] = bk;
}

extern "C" void kernel_launch(void* const* d_in, const int* in_sizes, int n_in,
                              void* d_out, int out_size, void* d_ws, size_t ws_size,
                              hipStream_t stream) {
    const float* z   = (const float*)d_in[0];   // [16,256,64,64]
    const float* emb = (const float*)d_in[1];   // [1024,256]
    int* out = (int*)d_out;                     // [65536] int32

    float* wsA   = (float*)d_ws;                    // 65536
    float* wsEE  = wsA + N_TOT;                     // 1024
    float* wsEPK = wsEE + K_DIM;                    // 262144
    float* wsPV  = wsEPK + (size_t)D_DIM * K_DIM;   // 8*65536
    int*   wsPK  = (int*)(wsPV + (size_t)NSPLIT * N_TOT);  // 8*65536

    pack_kernel<<<K_DIM, 256, 0, stream>>>(emb, wsEPK);
    ee_kernel<<<K_DIM / 256, 256, 0, stream>>>(emb, wsEE);
    a_kernel<<<N_TOT / 256, 256, 0, stream>>>(z, wsA);
    vq_partial<<<(N_TOT / 512) * NSPLIT, 256, 0, stream>>>(z, wsEPK, wsA, wsEE, wsPV, wsPK);
    combine_kernel<<<N_TOT / 256, 256, 0, stream>>>(wsPV, wsPK, out);
}